// Round 1
// baseline (246.573 us; speedup 1.0000x reference)
//
#include <hip/hip_runtime.h>
#include <hip/hip_bf16.h>
#include <stdint.h>

// ---------------------------------------------------------------------------
// E=64 H=64 PRE1=512 BNK=1024 S=256 P=16 B=4096. Attention branch dead
// (softmax over size-1 axis == 1). Decomposition (rel is rank-2):
//   Z1[s,i,j,k] = rx*MX[k] + ry*MY[k] + HH[16s+j][k];  Y1 = relu(Z1)
//   out = maxpool_j relu(bn2(Y1 @ Wp2))
// v11: Phase C retiled to mfma_f32_32x32x16_bf16. v10 was latency-bound:
//   per t-iter 64 MFMA = ~1242 SIMD-cyc vs ~3060 measured; B prefetch lead
//   (~154 cyc) < L2 latency (200-450), waves in lockstep stall together.
//   New tiling: wave = ALL 128 rows (4 rowtiles of 32) x 2 coltiles/chunk.
//   Per k-step: 8 MFMA (256 SIMD-cyc) fed by 2 B-loads + 4 A-ds_reads.
//   Ring-of-3 B prefetch (24 VGPR, ~2-iter/500+cyc lead) + A double-buffer
//   (256-cyc lead) -> steady-state stall-free at 2 waves/SIMD.
//   Y1 swizzle chunk^(r&7) stays: conflict-free for 32-row frags, and
//   (chunk&~7) is additive -> A addr = base[rt][k&3] + (k>>2)*128 (imm).
//   Epilogue: 32x32 C-layout needs only ONE shfl_xor(32) for maxpool.
//   setprio(1) around MFMA bursts (T5). Phases A/B unchanged.
//   LDS = Y1 128K + HH 16K = 144 KB, 1 WG/CU, 8 waves, no K-loop barriers.
// ---------------------------------------------------------------------------

typedef __bf16 bf16x8 __attribute__((ext_vector_type(8)));
typedef __bf16 bf16x2 __attribute__((ext_vector_type(2)));
typedef float  f32x4  __attribute__((ext_vector_type(4)));
typedef float  f32x2  __attribute__((ext_vector_type(2)));
typedef float  f32x16 __attribute__((ext_vector_type(16)));

// workspace layout (bytes)
#define BP2_OFF 0u          // packed Wp2, 32x32x16 B-frags: [kstep(32)][ct(32)][l(64)]*16B = 1 MB
#define BP1_OFF 1048576u    // packed W1b (Wp1 rows 64..127): [nt(32)][kb(2)][l]*16B = 64 KB
#define MX_OFF  1114112u    // 512 f32
#define MY_OFF  1116160u
#define CB_OFF  1118208u
#define SH_OFF  1120256u
#define A2_OFF  1122304u    // 1024 f32
#define C2_OFF  1126400u

// mm2 LDS layout (bytes)
#define Y1_LDS  0           // bf16 [128 r][512 k], row stride 1024 B, off = ((c16^(r&7))<<4)
#define HH_LDS  131072      // bf16 [16 j][512 k], row stride 1024 B
#define LDS_SZ  147456      // 144 KB

__device__ __forceinline__ unsigned short f2bf(float f) {
    union { float f; unsigned u; } c; c.f = f;
    unsigned u = c.u;
    return (unsigned short)((u + 0x7fffu + ((u >> 16) & 1u)) >> 16);
}
__device__ __forceinline__ float bfbits2f(unsigned hi) {
    union { unsigned u; float f; } c; c.u = hi; return c.f;
}
__device__ __forceinline__ unsigned pk_bf16(float a, float b) {
#if __has_builtin(__builtin_amdgcn_cvt_pk_bf16_f32)
    bf16x2 p = __builtin_amdgcn_cvt_pk_bf16_f32(a, b);
    union { bf16x2 v; unsigned u; } c; c.v = p; return c.u;
#else
    return (unsigned)f2bf(a) | ((unsigned)f2bf(b) << 16);
#endif
}
// Y1 address: row r (0..127), 16-byte chunk c16 (0..63).
__device__ __forceinline__ int y1off(int r, int c16) {
    return r * 1024 + ((c16 ^ (r & 7)) << 4);
}

// ---------------------------------------------------------------------------
// prep_pack: blocks 0..255 pack Wp2 into 32x32x16 B-frag layout
// ([kstep][ct][l]); 256..271 pack W1b (16x16x32 layout for Phase A);
// 272..273 fold k-consts; 274..277 fold A2/C2. All global reads coalesced.
// 32x32x16 B-frag: lane l holds B[k=kstep*16+(l>>5)*8+j][n=ct*32+(l&31)].
// 16x16x32 B-frag: lane l holds B[k=kb*32+(l>>4)*8+j][n=nt*16+(l&15)].
// ---------------------------------------------------------------------------
__global__ __launch_bounds__(256) void prep_pack_kernel(
    const float* __restrict__ Wsp,  const float* __restrict__ bsp,
    const float* __restrict__ Wp1,  const float* __restrict__ bp1,
    const float* __restrict__ gp1,  const float* __restrict__ btp1,
    const float* __restrict__ mp1,  const float* __restrict__ vp1,
    const float* __restrict__ Wp2,  const float* __restrict__ bp2,
    const float* __restrict__ gp2,  const float* __restrict__ btp2,
    const float* __restrict__ mp2,  const float* __restrict__ vp2,
    unsigned char* __restrict__ ws)
{
    __shared__ float tile[32 * 65];
    const int blk = blockIdx.x, t = threadIdx.x;

    if (blk < 272) {
        const float* src; int ncols, kb, ng;
        if (blk < 256) { kb = blk >> 4; ng = blk & 15; src = Wp2; ncols = 1024; }
        else { int b2 = blk - 256; kb = b2 >> 3; ng = b2 & 7; src = Wp1 + 64 * 512; ncols = 512; }
        const int k0 = kb * 32, n0 = ng * 64;
        #pragma unroll
        for (int it = 0; it < 2; ++it) {
            int c = t + it * 256;
            int r = c >> 4, c4 = c & 15;
            float4 v = *(const float4*)(src + (k0 + r) * ncols + n0 + c4 * 4);
            tile[r * 65 + c4 * 4 + 0] = v.x;
            tile[r * 65 + c4 * 4 + 1] = v.y;
            tile[r * 65 + c4 * 4 + 2] = v.z;
            tile[r * 65 + c4 * 4 + 3] = v.w;
        }
        __syncthreads();
        if (blk < 256) {
            // 32x32x16 B-frags: 2 ksteps x 2 coltiles per 32x64 tile
            const int l = t & 63, ch = (t >> 6) & 1, kh = t >> 7;
            const int nl = ch * 32 + (l & 31);
            const int kl = kh * 16 + ((l >> 5) & 1) * 8;
            uint4 o;
            o.x = pk_bf16(tile[(kl + 0) * 65 + nl], tile[(kl + 1) * 65 + nl]);
            o.y = pk_bf16(tile[(kl + 2) * 65 + nl], tile[(kl + 3) * 65 + nl]);
            o.z = pk_bf16(tile[(kl + 4) * 65 + nl], tile[(kl + 5) * 65 + nl]);
            o.w = pk_bf16(tile[(kl + 6) * 65 + nl], tile[(kl + 7) * 65 + nl]);
            const int kstep = kb * 2 + kh, ct = ng * 2 + ch;
            ((uint4*)(ws + BP2_OFF))[(kstep * 32 + ct) * 64 + l] = o;
        } else {
            // 16x16x32 B-frags for Phase A (unchanged layout)
            int ntl = t >> 6, l = t & 63;
            int nl = ntl * 16 + (l & 15), kl = (l >> 4) * 8;
            uint4 o;
            o.x = pk_bf16(tile[(kl + 0) * 65 + nl], tile[(kl + 1) * 65 + nl]);
            o.y = pk_bf16(tile[(kl + 2) * 65 + nl], tile[(kl + 3) * 65 + nl]);
            o.z = pk_bf16(tile[(kl + 4) * 65 + nl], tile[(kl + 5) * 65 + nl]);
            o.w = pk_bf16(tile[(kl + 6) * 65 + nl], tile[(kl + 7) * 65 + nl]);
            ((uint4*)(ws + BP1_OFF))[((ng * 4 + ntl) * 2 + kb) * 64 + l] = o;
        }
    } else if (blk < 274) {
        int k = (blk - 272) * 256 + t;
        float a1 = gp1[k] * rsqrtf(vp1[k] + 1e-5f);
        float mx = 0.f, my = 0.f, cb = 0.f;
        for (int e = 0; e < 64; ++e) {
            float wv = Wp1[e * 512 + k];
            mx = fmaf(Wsp[e],      wv, mx);
            my = fmaf(Wsp[64 + e], wv, my);
            cb = fmaf(bsp[e],      wv, cb);
        }
        ((float*)(ws + MX_OFF))[k] = 0.05f * a1 * mx;
        ((float*)(ws + MY_OFF))[k] = 0.05f * a1 * my;
        ((float*)(ws + CB_OFF))[k] = 0.05f * a1 * cb + (bp1[k] - mp1[k]) * a1 + btp1[k];
        ((float*)(ws + SH_OFF))[k] = 0.05f * a1;
    } else {
        int n = (blk - 274) * 256 + t;
        float a = gp2[n] * rsqrtf(vp2[n] + 1e-5f);
        ((float*)(ws + A2_OFF))[n] = a;
        ((float*)(ws + C2_OFF))[n] = btp2[n] + (bp2[n] - mp2[n]) * a;
    }
}

// ---------------------------------------------------------------------------
// mm2 v11: WG = (scene s, i-half ih). 512 thr = 8 waves.
// Phase A (1 barrier): HH[16x512] via 8 MFMA/wave from h x packed W1b.
// Phase B (1 barrier): construct Y1[128x512] bf16 (MX/MY/pos from global).
// Phase C (no barriers): 32x32x16 GEMM. Wave = 4 rowtiles(32) x 2 coltiles
//   per chunk; ring-of-3 B prefetch + A double-buffer; setprio on bursts.
// ---------------------------------------------------------------------------
__global__ __launch_bounds__(512, 2) void mm2_kernel(
    const float* __restrict__ hst,
    const float* __restrict__ epos,
    const unsigned char* __restrict__ ws,
    float* __restrict__ out)
{
    __shared__ __align__(16) unsigned char smem[LDS_SZ];

    const int s   = blockIdx.x >> 1;     // 256 scenes
    const int ih  = blockIdx.x & 1;      // i-half
    const int tid = threadIdx.x;
    const int w    = tid >> 6;           // 0..7
    const int l    = tid & 63;
    const int quad = l >> 4;
    const int jl   = l & 15;

    // ---- Phase A: HH via MFMA (16x16x32, unchanged) ----
    {
        union { unsigned u[4]; bf16x8 v; } afh[2];
        #pragma unroll
        for (int kb = 0; kb < 2; ++kb) {
            const float4* hp = (const float4*)(hst + (s * 16 + jl) * 64 + kb * 32 + quad * 8);
            float4 v0 = hp[0], v1 = hp[1];
            afh[kb].u[0] = pk_bf16(v0.x, v0.y);
            afh[kb].u[1] = pk_bf16(v0.z, v0.w);
            afh[kb].u[2] = pk_bf16(v1.x, v1.y);
            afh[kb].u[3] = pk_bf16(v1.z, v1.w);
        }
        const f32x4 fz = {0.f, 0.f, 0.f, 0.f};
        f32x4 acch[4] = {fz, fz, fz, fz};     // wave w -> k-cols w*64..+63
        #pragma unroll
        for (int kb = 0; kb < 2; ++kb) {
            #pragma unroll
            for (int ct = 0; ct < 4; ++ct) {
                bf16x8 bfr = *(const bf16x8*)(ws + BP1_OFF + ((((w * 4 + ct) * 2 + kb) * 64 + l) << 4));
                acch[ct] = __builtin_amdgcn_mfma_f32_16x16x32_bf16(afh[kb].v, bfr, acch[ct], 0, 0, 0);
            }
        }
        const float* SHg = (const float*)(ws + SH_OFF);
        const float* CBg = (const float*)(ws + CB_OFF);
        #pragma unroll
        for (int ct = 0; ct < 4; ++ct) {
            int col = (w * 4 + ct) * 16 + jl;        // k index
            float sh = SHg[col], cb = CBg[col];
            #pragma unroll
            for (int reg = 0; reg < 4; ++reg) {
                int j = quad * 4 + reg;
                float hv = fmaf(acch[ct][reg], sh, cb);
                *(unsigned short*)(smem + HH_LDS + j * 1024 + col * 2) = f2bf(hv);
            }
        }
    }
    __syncthreads();

    // ---- Phase B: construct Y1 (bf16, swizzled); MX/MY/pos from global ----
    {
        const int i2 = tid >> 8;           // 0..1  (4 i each)
        const int j  = (tid >> 4) & 15;
        const int kc = tid & 15;           // k0 = kc*32
        float rx[4], ry[4];
        float pjx = epos[s * 32 + j * 2], pjy = epos[s * 32 + j * 2 + 1];
        #pragma unroll
        for (int ii = 0; ii < 4; ++ii) {
            int ig_ = ih * 8 + i2 * 4 + ii;
            rx[ii] = pjx - epos[s * 32 + ig_ * 2];
            ry[ii] = pjy - epos[s * 32 + ig_ * 2 + 1];
        }
        const f32x2 zero2 = {0.f, 0.f};
        #pragma unroll
        for (int kk = 0; kk < 4; ++kk) {
            int k = kc * 32 + kk * 8;
            uint4 hh8 = *(const uint4*)(smem + HH_LDS + j * 1024 + k * 2);
            f32x4 mx0 = *(const f32x4*)(ws + MX_OFF + k * 4);
            f32x4 mx1 = *(const f32x4*)(ws + MX_OFF + k * 4 + 16);
            f32x4 my0 = *(const f32x4*)(ws + MY_OFF + k * 4);
            f32x4 my1 = *(const f32x4*)(ws + MY_OFF + k * 4 + 16);
            f32x2 mxp[4] = { {mx0[0],mx0[1]}, {mx0[2],mx0[3]}, {mx1[0],mx1[1]}, {mx1[2],mx1[3]} };
            f32x2 myp[4] = { {my0[0],my0[1]}, {my0[2],my0[3]}, {my1[0],my1[1]}, {my1[2],my1[3]} };
            f32x2 hhp[4];
            hhp[0][0] = bfbits2f(hh8.x << 16); hhp[0][1] = bfbits2f(hh8.x & 0xffff0000u);
            hhp[1][0] = bfbits2f(hh8.y << 16); hhp[1][1] = bfbits2f(hh8.y & 0xffff0000u);
            hhp[2][0] = bfbits2f(hh8.z << 16); hhp[2][1] = bfbits2f(hh8.z & 0xffff0000u);
            hhp[3][0] = bfbits2f(hh8.w << 16); hhp[3][1] = bfbits2f(hh8.w & 0xffff0000u);
            #pragma unroll
            for (int ii = 0; ii < 4; ++ii) {
                f32x2 rx2 = { rx[ii], rx[ii] };
                f32x2 ry2 = { ry[ii], ry[ii] };
                uint4 o;
                unsigned uu[4];
                #pragma unroll
                for (int p = 0; p < 4; ++p) {
                    f32x2 tt = __builtin_elementwise_fma(ry2, myp[p], hhp[p]);
                    tt = __builtin_elementwise_fma(rx2, mxp[p], tt);
                    tt = __builtin_elementwise_max(tt, zero2);
                    uu[p] = pk_bf16(tt[0], tt[1]);
                }
                o.x = uu[0]; o.y = uu[1]; o.z = uu[2]; o.w = uu[3];
                int r = (i2 * 4 + ii) * 16 + j;
                *(uint4*)(smem + Y1_LDS + y1off(r, kc * 4 + kk)) = o;
            }
        }
    }
    __syncthreads();

    // ---- Phase C: 32x32x16 GEMM, no barriers ----
    {
        const int lane31 = l & 31;           // = A-frag m within 32-row tile, = C col
        const int hi = l >> 5;               // k-half of A/B frags; C row group
        const int sr = lane31 & 7;           // r&7 for all rowtiles (rows rt*32+lane31)
        const float* A2 = (const float*)(ws + A2_OFF);
        const float* C2 = (const float*)(ws + C2_OFF);

        // A base addrs: addr(rt,k) = av[rt][k&3] + (k>>2)*128  (imm offset)
        // chunk = k*2+hi; swizzled = (chunk&~7) | ((chunk&7)^sr);
        // chunk&~7 = (k>>2)<<3 (additive); chunk&7 = ((k&3)<<1)|hi.
        int av[4][4];
        #pragma unroll
        for (int rt = 0; rt < 4; ++rt)
            #pragma unroll
            for (int km = 0; km < 4; ++km)
                av[rt][km] = Y1_LDS + (rt * 32 + lane31) * 1024
                           + (((((km << 1) | hi) ^ sr)) << 4);

        const f32x16 fz16 = {0.f,0.f,0.f,0.f,0.f,0.f,0.f,0.f,
                             0.f,0.f,0.f,0.f,0.f,0.f,0.f,0.f};

        #pragma unroll 1
        for (int chunk = 0; chunk < 2; ++chunk) {
            const int ctbase = w * 4 + chunk * 2;
            const unsigned char* bp = ws + BP2_OFF + (ctbase << 10) + (l << 4);
            // B addr = bp + kstep*32768 + c*1024

            f32x16 acc[4][2];
            #pragma unroll
            for (int rt = 0; rt < 4; ++rt) { acc[rt][0] = fz16; acc[rt][1] = fz16; }

            bf16x8 aA[4], aB[4];
            bf16x8 br[3][2];
            #pragma unroll
            for (int rt = 0; rt < 4; ++rt)
                aA[rt] = *(const bf16x8*)(smem + av[rt][0]);
            #pragma unroll
            for (int kp = 0; kp < 3; ++kp) {
                br[kp][0] = *(const bf16x8*)(bp + kp * 32768);
                br[kp][1] = *(const bf16x8*)(bp + kp * 32768 + 1024);
            }

            #pragma unroll
            for (int k = 0; k < 32; ++k) {
                // A double-buffer: read k+1 (lead ~256 SIMD-cyc)
                if (k < 31) {
                    const int kn = k + 1;
                    if ((k & 1) == 0) {
                        #pragma unroll
                        for (int rt = 0; rt < 4; ++rt)
                            aB[rt] = *(const bf16x8*)(smem + av[rt][kn & 3] + (kn >> 2) * 128);
                    } else {
                        #pragma unroll
                        for (int rt = 0; rt < 4; ++rt)
                            aA[rt] = *(const bf16x8*)(smem + av[rt][kn & 3] + (kn >> 2) * 128);
                    }
                }
                // 8-MFMA burst (~256 SIMD-cyc)
                __builtin_amdgcn_s_setprio(1);
                if ((k & 1) == 0) {
                    #pragma unroll
                    for (int c = 0; c < 2; ++c)
                        #pragma unroll
                        for (int rt = 0; rt < 4; ++rt)
                            acc[rt][c] = __builtin_amdgcn_mfma_f32_32x32x16_bf16(
                                aA[rt], br[k % 3][c], acc[rt][c], 0, 0, 0);
                } else {
                    #pragma unroll
                    for (int c = 0; c < 2; ++c)
                        #pragma unroll
                        for (int rt = 0; rt < 4; ++rt)
                            acc[rt][c] = __builtin_amdgcn_mfma_f32_32x32x16_bf16(
                                aB[rt], br[k % 3][c], acc[rt][c], 0, 0, 0);
                }
                __builtin_amdgcn_s_setprio(0);
                // ring-of-3 B prefetch: issue k+3 into just-freed slot (lead ~2 iters)
                if (k < 29) {
                    br[k % 3][0] = *(const bf16x8*)(bp + (k + 3) * 32768);
                    br[k % 3][1] = *(const bf16x8*)(bp + (k + 3) * 32768 + 1024);
                }
            }

            // epilogue: bn2 + relu, maxpool over j, store fp32.
            // C/D 32x32: col = lane&31, row = (reg&3)+8*(reg>>2)+4*hi.
            // regs 0..7  -> tile rows 0..15  (i_local = rt*2):   j in {0-3,8-11}+4hi
            // regs 8..15 -> tile rows 16..31 (i_local = rt*2+1): same pattern
            // full 16-j max = max(own 8 regs, shfl_xor 32).
            #pragma unroll
            for (int c = 0; c < 2; ++c) {
                const int col = (ctbase + c) * 32 + lane31;
                const float a2 = A2[col], c2v = C2[col];
                #pragma unroll
                for (int rt = 0; rt < 4; ++rt) {
                    float mv[2];
                    #pragma unroll
                    for (int hg = 0; hg < 2; ++hg) {
                        float v0 = fmaxf(fmaf(acc[rt][c][hg * 8 + 0], a2, c2v), 0.f);
                        float v1 = fmaxf(fmaf(acc[rt][c][hg * 8 + 1], a2, c2v), 0.f);
                        float v2 = fmaxf(fmaf(acc[rt][c][hg * 8 + 2], a2, c2v), 0.f);
                        float v3 = fmaxf(fmaf(acc[rt][c][hg * 8 + 3], a2, c2v), 0.f);
                        float v4 = fmaxf(fmaf(acc[rt][c][hg * 8 + 4], a2, c2v), 0.f);
                        float v5 = fmaxf(fmaf(acc[rt][c][hg * 8 + 5], a2, c2v), 0.f);
                        float v6 = fmaxf(fmaf(acc[rt][c][hg * 8 + 6], a2, c2v), 0.f);
                        float v7 = fmaxf(fmaf(acc[rt][c][hg * 8 + 7], a2, c2v), 0.f);
                        float m = fmaxf(fmaxf(fmaxf(v0, v1), fmaxf(v2, v3)),
                                        fmaxf(fmaxf(v4, v5), fmaxf(v6, v7)));
                        mv[hg] = fmaxf(m, __shfl_xor(m, 32, 64));
                    }
                    const int iloc = rt * 2 + hi;       // hi=0 stores even i, hi=1 odd
                    const float vout = hi ? mv[1] : mv[0];
                    const int orow = s * 16 + ih * 8 + iloc;
                    __builtin_nontemporal_store(vout, &out[orow * 1024 + col]);
                }
            }
        }
    }
}

extern "C" void kernel_launch(void* const* d_in, const int* in_sizes, int n_in,
                              void* d_out, int out_size, void* d_ws, size_t ws_size,
                              hipStream_t stream) {
    const float* hst  = (const float*)d_in[0];
    const float* epos = (const float*)d_in[1];
    const float* Wsp  = (const float*)d_in[4];
    const float* bsp  = (const float*)d_in[5];
    const float* Wp1  = (const float*)d_in[20];
    const float* bp1  = (const float*)d_in[21];
    const float* gp1  = (const float*)d_in[22];
    const float* btp1 = (const float*)d_in[23];
    const float* mp1  = (const float*)d_in[24];
    const float* vp1  = (const float*)d_in[25];
    const float* Wp2  = (const float*)d_in[26];
    const float* bp2  = (const float*)d_in[27];
    const float* gp2  = (const float*)d_in[28];
    const float* btp2 = (const float*)d_in[29];
    const float* mp2  = (const float*)d_in[30];
    const float* vp2  = (const float*)d_in[31];
    unsigned char* ws = (unsigned char*)d_ws;
    float* out = (float*)d_out;

    // 256 (Wp2 pack) + 16 (W1b pack) + 2 (k-consts) + 4 (A2/C2) = 278 blocks
    prep_pack_kernel<<<278, 256, 0, stream>>>(Wsp, bsp, Wp1, bp1, gp1, btp1, mp1, vp1,
                                              Wp2, bp2, gp2, btp2, mp2, vp2, ws);
    // 256 scenes x 2 i-halves, 512 threads (8 waves)
    mm2_kernel<<<512, 512, 0, stream>>>(hst, epos, ws, out);
}

// Round 2
// 192.109 us; speedup vs baseline: 1.2835x; 1.2835x over previous
//
#include <hip/hip_runtime.h>
#include <hip/hip_bf16.h>
#include <stdint.h>

// ---------------------------------------------------------------------------
// E=64 H=64 PRE1=512 BNK=1024 S=256 P=16 B=4096. Attention branch dead
// (softmax over size-1 axis == 1). Decomposition (rel is rank-2):
//   Z1[s,i,j,k] = rx*MX[k] + ry*MY[k] + HH[16s+j][k];  Y1 = relu(Z1)
//   out = maxpool_j relu(bn2(Y1 @ Wp2))
// v12: v11's 32x32x16 tiling, spill-free. v11 spilled (FETCH 206MB/WRITE
//   213MB = scratch traffic; full 32x k-unroll + av[16] + ring%3 pushed
//   live set past the 256-reg unified budget at 2 waves/SIMD). v12:
//   (1) av[4] only; addr(rt,k) = (av[rt] + (k>>2)*128) ^ ((k&3)<<5)
//       (algebraically identical to v11's av[4][4] table);
//   (2) k-loop = unroll-1 over 8 groups of 4 ksteps (bounded live ranges);
//   (3) B ring-of-4 br[4][2], prefetch distance 3 ksteps (~380cyc lead
//       >= L2 latency); A double-buffer a0/a1, 1 kstep ahead;
//   (4) last group peeled -> all B reads within BP2 (no ws overrun).
//   Regs: acc 128 + a 32 + br 32 + av 4 + temps ~15 = ~210 < 256.
//   LDS = Y1 128K + HH 16K = 144 KB, 1 WG/CU, 8 waves, no K-loop barriers.
// ---------------------------------------------------------------------------

typedef __bf16 bf16x8 __attribute__((ext_vector_type(8)));
typedef __bf16 bf16x2 __attribute__((ext_vector_type(2)));
typedef float  f32x4  __attribute__((ext_vector_type(4)));
typedef float  f32x2  __attribute__((ext_vector_type(2)));
typedef float  f32x16 __attribute__((ext_vector_type(16)));

// workspace layout (bytes)
#define BP2_OFF 0u          // packed Wp2, 32x32x16 B-frags: [kstep(32)][ct(32)][l(64)]*16B = 1 MB
#define BP1_OFF 1048576u    // packed W1b (Wp1 rows 64..127): [nt(32)][kb(2)][l]*16B = 64 KB
#define MX_OFF  1114112u    // 512 f32
#define MY_OFF  1116160u
#define CB_OFF  1118208u
#define SH_OFF  1120256u
#define A2_OFF  1122304u    // 1024 f32
#define C2_OFF  1126400u

// mm2 LDS layout (bytes)
#define Y1_LDS  0           // bf16 [128 r][512 k], row stride 1024 B, off = ((c16^(r&7))<<4)
#define HH_LDS  131072      // bf16 [16 j][512 k], row stride 1024 B
#define LDS_SZ  147456      // 144 KB

__device__ __forceinline__ unsigned short f2bf(float f) {
    union { float f; unsigned u; } c; c.f = f;
    unsigned u = c.u;
    return (unsigned short)((u + 0x7fffu + ((u >> 16) & 1u)) >> 16);
}
__device__ __forceinline__ float bfbits2f(unsigned hi) {
    union { unsigned u; float f; } c; c.u = hi; return c.f;
}
__device__ __forceinline__ unsigned pk_bf16(float a, float b) {
#if __has_builtin(__builtin_amdgcn_cvt_pk_bf16_f32)
    bf16x2 p = __builtin_amdgcn_cvt_pk_bf16_f32(a, b);
    union { bf16x2 v; unsigned u; } c; c.v = p; return c.u;
#else
    return (unsigned)f2bf(a) | ((unsigned)f2bf(b) << 16);
#endif
}
// Y1 address: row r (0..127), 16-byte chunk c16 (0..63).
__device__ __forceinline__ int y1off(int r, int c16) {
    return r * 1024 + ((c16 ^ (r & 7)) << 4);
}

// ---------------------------------------------------------------------------
// prep_pack: blocks 0..255 pack Wp2 into 32x32x16 B-frag layout
// ([kstep][ct][l]); 256..271 pack W1b (16x16x32 layout for Phase A);
// 272..273 fold k-consts; 274..277 fold A2/C2. All global reads coalesced.
// 32x32x16 B-frag: lane l holds B[k=kstep*16+(l>>5)*8+j][n=ct*32+(l&31)].
// 16x16x32 B-frag: lane l holds B[k=kb*32+(l>>4)*8+j][n=nt*16+(l&15)].
// ---------------------------------------------------------------------------
__global__ __launch_bounds__(256) void prep_pack_kernel(
    const float* __restrict__ Wsp,  const float* __restrict__ bsp,
    const float* __restrict__ Wp1,  const float* __restrict__ bp1,
    const float* __restrict__ gp1,  const float* __restrict__ btp1,
    const float* __restrict__ mp1,  const float* __restrict__ vp1,
    const float* __restrict__ Wp2,  const float* __restrict__ bp2,
    const float* __restrict__ gp2,  const float* __restrict__ btp2,
    const float* __restrict__ mp2,  const float* __restrict__ vp2,
    unsigned char* __restrict__ ws)
{
    __shared__ float tile[32 * 65];
    const int blk = blockIdx.x, t = threadIdx.x;

    if (blk < 272) {
        const float* src; int ncols, kb, ng;
        if (blk < 256) { kb = blk >> 4; ng = blk & 15; src = Wp2; ncols = 1024; }
        else { int b2 = blk - 256; kb = b2 >> 3; ng = b2 & 7; src = Wp1 + 64 * 512; ncols = 512; }
        const int k0 = kb * 32, n0 = ng * 64;
        #pragma unroll
        for (int it = 0; it < 2; ++it) {
            int c = t + it * 256;
            int r = c >> 4, c4 = c & 15;
            float4 v = *(const float4*)(src + (k0 + r) * ncols + n0 + c4 * 4);
            tile[r * 65 + c4 * 4 + 0] = v.x;
            tile[r * 65 + c4 * 4 + 1] = v.y;
            tile[r * 65 + c4 * 4 + 2] = v.z;
            tile[r * 65 + c4 * 4 + 3] = v.w;
        }
        __syncthreads();
        if (blk < 256) {
            // 32x32x16 B-frags: 2 ksteps x 2 coltiles per 32x64 tile
            const int l = t & 63, ch = (t >> 6) & 1, kh = t >> 7;
            const int nl = ch * 32 + (l & 31);
            const int kl = kh * 16 + ((l >> 5) & 1) * 8;
            uint4 o;
            o.x = pk_bf16(tile[(kl + 0) * 65 + nl], tile[(kl + 1) * 65 + nl]);
            o.y = pk_bf16(tile[(kl + 2) * 65 + nl], tile[(kl + 3) * 65 + nl]);
            o.z = pk_bf16(tile[(kl + 4) * 65 + nl], tile[(kl + 5) * 65 + nl]);
            o.w = pk_bf16(tile[(kl + 6) * 65 + nl], tile[(kl + 7) * 65 + nl]);
            const int kstep = kb * 2 + kh, ct = ng * 2 + ch;
            ((uint4*)(ws + BP2_OFF))[(kstep * 32 + ct) * 64 + l] = o;
        } else {
            // 16x16x32 B-frags for Phase A (unchanged layout)
            int ntl = t >> 6, l = t & 63;
            int nl = ntl * 16 + (l & 15), kl = (l >> 4) * 8;
            uint4 o;
            o.x = pk_bf16(tile[(kl + 0) * 65 + nl], tile[(kl + 1) * 65 + nl]);
            o.y = pk_bf16(tile[(kl + 2) * 65 + nl], tile[(kl + 3) * 65 + nl]);
            o.z = pk_bf16(tile[(kl + 4) * 65 + nl], tile[(kl + 5) * 65 + nl]);
            o.w = pk_bf16(tile[(kl + 6) * 65 + nl], tile[(kl + 7) * 65 + nl]);
            ((uint4*)(ws + BP1_OFF))[((ng * 4 + ntl) * 2 + kb) * 64 + l] = o;
        }
    } else if (blk < 274) {
        int k = (blk - 272) * 256 + t;
        float a1 = gp1[k] * rsqrtf(vp1[k] + 1e-5f);
        float mx = 0.f, my = 0.f, cb = 0.f;
        for (int e = 0; e < 64; ++e) {
            float wv = Wp1[e * 512 + k];
            mx = fmaf(Wsp[e],      wv, mx);
            my = fmaf(Wsp[64 + e], wv, my);
            cb = fmaf(bsp[e],      wv, cb);
        }
        ((float*)(ws + MX_OFF))[k] = 0.05f * a1 * mx;
        ((float*)(ws + MY_OFF))[k] = 0.05f * a1 * my;
        ((float*)(ws + CB_OFF))[k] = 0.05f * a1 * cb + (bp1[k] - mp1[k]) * a1 + btp1[k];
        ((float*)(ws + SH_OFF))[k] = 0.05f * a1;
    } else {
        int n = (blk - 274) * 256 + t;
        float a = gp2[n] * rsqrtf(vp2[n] + 1e-5f);
        ((float*)(ws + A2_OFF))[n] = a;
        ((float*)(ws + C2_OFF))[n] = btp2[n] + (bp2[n] - mp2[n]) * a;
    }
}

// ---------------------------------------------------------------------------
// mm2 v12: WG = (scene s, i-half ih). 512 thr = 8 waves.
// Phase A (1 barrier): HH[16x512] via 8 MFMA/wave from h x packed W1b.
// Phase B (1 barrier): construct Y1[128x512] bf16 (MX/MY/pos from global).
// Phase C (no barriers): 32x32x16 GEMM. Wave = 4 rowtiles(32) x 2 coltiles
//   per chunk; B ring-of-4 dist-3 prefetch; A double-buffer; setprio.
// ---------------------------------------------------------------------------
__global__ __launch_bounds__(512, 2) void mm2_kernel(
    const float* __restrict__ hst,
    const float* __restrict__ epos,
    const unsigned char* __restrict__ ws,
    float* __restrict__ out)
{
    __shared__ __align__(16) unsigned char smem[LDS_SZ];

    const int s   = blockIdx.x >> 1;     // 256 scenes
    const int ih  = blockIdx.x & 1;      // i-half
    const int tid = threadIdx.x;
    const int w    = tid >> 6;           // 0..7
    const int l    = tid & 63;
    const int quad = l >> 4;
    const int jl   = l & 15;

    // ---- Phase A: HH via MFMA (16x16x32, unchanged) ----
    {
        union { unsigned u[4]; bf16x8 v; } afh[2];
        #pragma unroll
        for (int kb = 0; kb < 2; ++kb) {
            const float4* hp = (const float4*)(hst + (s * 16 + jl) * 64 + kb * 32 + quad * 8);
            float4 v0 = hp[0], v1 = hp[1];
            afh[kb].u[0] = pk_bf16(v0.x, v0.y);
            afh[kb].u[1] = pk_bf16(v0.z, v0.w);
            afh[kb].u[2] = pk_bf16(v1.x, v1.y);
            afh[kb].u[3] = pk_bf16(v1.z, v1.w);
        }
        const f32x4 fz = {0.f, 0.f, 0.f, 0.f};
        f32x4 acch[4] = {fz, fz, fz, fz};     // wave w -> k-cols w*64..+63
        #pragma unroll
        for (int kb = 0; kb < 2; ++kb) {
            #pragma unroll
            for (int ct = 0; ct < 4; ++ct) {
                bf16x8 bfr = *(const bf16x8*)(ws + BP1_OFF + ((((w * 4 + ct) * 2 + kb) * 64 + l) << 4));
                acch[ct] = __builtin_amdgcn_mfma_f32_16x16x32_bf16(afh[kb].v, bfr, acch[ct], 0, 0, 0);
            }
        }
        const float* SHg = (const float*)(ws + SH_OFF);
        const float* CBg = (const float*)(ws + CB_OFF);
        #pragma unroll
        for (int ct = 0; ct < 4; ++ct) {
            int col = (w * 4 + ct) * 16 + jl;        // k index
            float sh = SHg[col], cb = CBg[col];
            #pragma unroll
            for (int reg = 0; reg < 4; ++reg) {
                int j = quad * 4 + reg;
                float hv = fmaf(acch[ct][reg], sh, cb);
                *(unsigned short*)(smem + HH_LDS + j * 1024 + col * 2) = f2bf(hv);
            }
        }
    }
    __syncthreads();

    // ---- Phase B: construct Y1 (bf16, swizzled); MX/MY/pos from global ----
    {
        const int i2 = tid >> 8;           // 0..1  (4 i each)
        const int j  = (tid >> 4) & 15;
        const int kc = tid & 15;           // k0 = kc*32
        float rx[4], ry[4];
        float pjx = epos[s * 32 + j * 2], pjy = epos[s * 32 + j * 2 + 1];
        #pragma unroll
        for (int ii = 0; ii < 4; ++ii) {
            int ig_ = ih * 8 + i2 * 4 + ii;
            rx[ii] = pjx - epos[s * 32 + ig_ * 2];
            ry[ii] = pjy - epos[s * 32 + ig_ * 2 + 1];
        }
        const f32x2 zero2 = {0.f, 0.f};
        #pragma unroll
        for (int kk = 0; kk < 4; ++kk) {
            int k = kc * 32 + kk * 8;
            uint4 hh8 = *(const uint4*)(smem + HH_LDS + j * 1024 + k * 2);
            f32x4 mx0 = *(const f32x4*)(ws + MX_OFF + k * 4);
            f32x4 mx1 = *(const f32x4*)(ws + MX_OFF + k * 4 + 16);
            f32x4 my0 = *(const f32x4*)(ws + MY_OFF + k * 4);
            f32x4 my1 = *(const f32x4*)(ws + MY_OFF + k * 4 + 16);
            f32x2 mxp[4] = { {mx0[0],mx0[1]}, {mx0[2],mx0[3]}, {mx1[0],mx1[1]}, {mx1[2],mx1[3]} };
            f32x2 myp[4] = { {my0[0],my0[1]}, {my0[2],my0[3]}, {my1[0],my1[1]}, {my1[2],my1[3]} };
            f32x2 hhp[4];
            hhp[0][0] = bfbits2f(hh8.x << 16); hhp[0][1] = bfbits2f(hh8.x & 0xffff0000u);
            hhp[1][0] = bfbits2f(hh8.y << 16); hhp[1][1] = bfbits2f(hh8.y & 0xffff0000u);
            hhp[2][0] = bfbits2f(hh8.z << 16); hhp[2][1] = bfbits2f(hh8.z & 0xffff0000u);
            hhp[3][0] = bfbits2f(hh8.w << 16); hhp[3][1] = bfbits2f(hh8.w & 0xffff0000u);
            #pragma unroll
            for (int ii = 0; ii < 4; ++ii) {
                f32x2 rx2 = { rx[ii], rx[ii] };
                f32x2 ry2 = { ry[ii], ry[ii] };
                uint4 o;
                unsigned uu[4];
                #pragma unroll
                for (int p = 0; p < 4; ++p) {
                    f32x2 tt = __builtin_elementwise_fma(ry2, myp[p], hhp[p]);
                    tt = __builtin_elementwise_fma(rx2, mxp[p], tt);
                    tt = __builtin_elementwise_max(tt, zero2);
                    uu[p] = pk_bf16(tt[0], tt[1]);
                }
                o.x = uu[0]; o.y = uu[1]; o.z = uu[2]; o.w = uu[3];
                int r = (i2 * 4 + ii) * 16 + j;
                *(uint4*)(smem + Y1_LDS + y1off(r, kc * 4 + kk)) = o;
            }
        }
    }
    __syncthreads();

    // ---- Phase C: 32x32x16 GEMM, no barriers ----
    {
        const int lane31 = l & 31;           // = A-frag m within 32-row tile, = C col
        const int hi = l >> 5;               // k-half of A/B frags; C row group
        const int sr = lane31 & 7;           // r&7 for all rowtiles (rows rt*32+lane31)
        const float* A2 = (const float*)(ws + A2_OFF);
        const float* C2 = (const float*)(ws + C2_OFF);

        // addr(rt,kstep) = (av[rt] + (kstep>>2)*128) ^ ((kstep&3)<<5)
        // (equiv to v11's av[4][4] table: ((m<<1)|hi)^sr = (hi^sr)^(m<<1),
        //  shift distributes over XOR, +k128 only touches bits >= 7)
        int av[4];
        #pragma unroll
        for (int rt = 0; rt < 4; ++rt)
            av[rt] = Y1_LDS + (rt * 32 + lane31) * 1024 + ((hi ^ sr) << 4);

        const f32x16 fz16 = {0.f,0.f,0.f,0.f,0.f,0.f,0.f,0.f,
                             0.f,0.f,0.f,0.f,0.f,0.f,0.f,0.f};

        #pragma unroll 1
        for (int chunk = 0; chunk < 2; ++chunk) {
            const int ctbase = w * 4 + chunk * 2;
            const unsigned char* bp = ws + BP2_OFF + (ctbase << 10) + (l << 4);
            // B addr = bp + kstep*32768 + c*1024

            f32x16 acc[4][2];
            #pragma unroll
            for (int rt = 0; rt < 4; ++rt) { acc[rt][0] = fz16; acc[rt][1] = fz16; }

            bf16x8 a0[4], a1[4];   // A double-buffer
            bf16x8 br[4][2];       // B ring-of-4, slot = kstep & 3

            auto ldA = [&](bf16x8* dst, int add, int xorv) {
                #pragma unroll
                for (int rt = 0; rt < 4; ++rt)
                    dst[rt] = *(const bf16x8*)(smem + ((av[rt] + add) ^ xorv));
            };
            auto ldB = [&](bf16x8* slot, const unsigned char* base, int off) {
                slot[0] = *(const bf16x8*)(base + off);
                slot[1] = *(const bf16x8*)(base + off + 1024);
            };
            auto mfma8 = [&](const bf16x8* a, const bf16x8* b) {
                __builtin_amdgcn_s_setprio(1);
                #pragma unroll
                for (int c = 0; c < 2; ++c)
                    #pragma unroll
                    for (int rt = 0; rt < 4; ++rt)
                        acc[rt][c] = __builtin_amdgcn_mfma_f32_32x32x16_bf16(
                            a[rt], b[c], acc[rt][c], 0, 0, 0);
                __builtin_amdgcn_s_setprio(0);
            };

            // prologue: B ksteps 0,1,2 (dist-3 ring); A kstep 0
            ldB(br[0], bp, 0);
            ldB(br[1], bp, 32768);
            ldB(br[2], bp, 65536);
            ldA(a0, 0, 0);

            #pragma unroll 1
            for (int kq = 0; kq < 7; ++kq) {
                const unsigned char* bq = bp + kq * 131072;
                const int ka = kq * 128;
                // m=0: kstep 4kq; prefetch B kstep+3 -> slot 3, A kstep+1
                ldB(br[3], bq, 98304);
                ldA(a1, ka, 32);
                mfma8(a0, br[0]);
                // m=1: prefetch B -> slot 0 (kstep 4kq+4), A 4kq+2
                ldB(br[0], bq, 131072);
                ldA(a0, ka, 64);
                mfma8(a1, br[1]);
                // m=2: prefetch B -> slot 1 (4kq+5), A 4kq+3
                ldB(br[1], bq, 163840);
                ldA(a1, ka, 96);
                mfma8(a0, br[2]);
                // m=3: prefetch B -> slot 2 (4kq+6), A 4(kq+1)
                ldB(br[2], bq, 196608);
                ldA(a0, ka + 128, 0);
                mfma8(a1, br[3]);
            }
            // kq=7 peeled: only in-range prefetches (kstep 31 max)
            {
                const unsigned char* bq = bp + 7 * 131072;
                const int ka = 7 * 128;
                ldB(br[3], bq, 98304);   // kstep 31
                ldA(a1, ka, 32);
                mfma8(a0, br[0]);        // kstep 28
                ldA(a0, ka, 64);
                mfma8(a1, br[1]);        // kstep 29
                ldA(a1, ka, 96);
                mfma8(a0, br[2]);        // kstep 30
                mfma8(a1, br[3]);        // kstep 31
            }

            // epilogue: bn2 + relu, maxpool over j, store fp32.
            // C/D 32x32: col = lane&31, row = (reg&3)+8*(reg>>2)+4*hi.
            // regs 0..7  -> tile rows 0..15  (i_local = rt*2)
            // regs 8..15 -> tile rows 16..31 (i_local = rt*2+1)
            // full 16-j max = max(own 8 regs, shfl_xor 32).
            #pragma unroll
            for (int c = 0; c < 2; ++c) {
                const int col = (ctbase + c) * 32 + lane31;
                const float a2 = A2[col], c2v = C2[col];
                #pragma unroll
                for (int rt = 0; rt < 4; ++rt) {
                    float mv[2];
                    #pragma unroll
                    for (int hg = 0; hg < 2; ++hg) {
                        float v0 = fmaxf(fmaf(acc[rt][c][hg * 8 + 0], a2, c2v), 0.f);
                        float v1 = fmaxf(fmaf(acc[rt][c][hg * 8 + 1], a2, c2v), 0.f);
                        float v2 = fmaxf(fmaf(acc[rt][c][hg * 8 + 2], a2, c2v), 0.f);
                        float v3 = fmaxf(fmaf(acc[rt][c][hg * 8 + 3], a2, c2v), 0.f);
                        float v4 = fmaxf(fmaf(acc[rt][c][hg * 8 + 4], a2, c2v), 0.f);
                        float v5 = fmaxf(fmaf(acc[rt][c][hg * 8 + 5], a2, c2v), 0.f);
                        float v6 = fmaxf(fmaf(acc[rt][c][hg * 8 + 6], a2, c2v), 0.f);
                        float v7 = fmaxf(fmaf(acc[rt][c][hg * 8 + 7], a2, c2v), 0.f);
                        float m = fmaxf(fmaxf(fmaxf(v0, v1), fmaxf(v2, v3)),
                                        fmaxf(fmaxf(v4, v5), fmaxf(v6, v7)));
                        mv[hg] = fmaxf(m, __shfl_xor(m, 32, 64));
                    }
                    const int iloc = rt * 2 + hi;       // hi=0 stores even i, hi=1 odd
                    const float vout = hi ? mv[1] : mv[0];
                    const int orow = s * 16 + ih * 8 + iloc;
                    __builtin_nontemporal_store(vout, &out[orow * 1024 + col]);
                }
            }
        }
    }
}

extern "C" void kernel_launch(void* const* d_in, const int* in_sizes, int n_in,
                              void* d_out, int out_size, void* d_ws, size_t ws_size,
                              hipStream_t stream) {
    const float* hst  = (const float*)d_in[0];
    const float* epos = (const float*)d_in[1];
    const float* Wsp  = (const float*)d_in[4];
    const float* bsp  = (const float*)d_in[5];
    const float* Wp1  = (const float*)d_in[20];
    const float* bp1  = (const float*)d_in[21];
    const float* gp1  = (const float*)d_in[22];
    const float* btp1 = (const float*)d_in[23];
    const float* mp1  = (const float*)d_in[24];
    const float* vp1  = (const float*)d_in[25];
    const float* Wp2  = (const float*)d_in[26];
    const float* bp2  = (const float*)d_in[27];
    const float* gp2  = (const float*)d_in[28];
    const float* btp2 = (const float*)d_in[29];
    const float* mp2  = (const float*)d_in[30];
    const float* vp2  = (const float*)d_in[31];
    unsigned char* ws = (unsigned char*)d_ws;
    float* out = (float*)d_out;

    // 256 (Wp2 pack) + 16 (W1b pack) + 2 (k-consts) + 4 (A2/C2) = 278 blocks
    prep_pack_kernel<<<278, 256, 0, stream>>>(Wsp, bsp, Wp1, bp1, gp1, btp1, mp1, vp1,
                                              Wp2, bp2, gp2, btp2, mp2, vp2, ws);
    // 256 scenes x 2 i-halves, 512 threads (8 waves)
    mm2_kernel<<<512, 512, 0, stream>>>(hst, epos, ws, out);
}

// Round 3
// 191.095 us; speedup vs baseline: 1.2903x; 1.0053x over previous
//
#include <hip/hip_runtime.h>
#include <hip/hip_bf16.h>
#include <stdint.h>

// ---------------------------------------------------------------------------
// E=64 H=64 PRE1=512 BNK=1024 S=256 P=16 B=4096. Attention branch dead
// (softmax over size-1 axis == 1). Decomposition (rel is rank-2):
//   Z1[s,i,j,k] = rx*MX[k] + ry*MY[k] + HH[16s+j][k];  Y1 = relu(Z1)
//   out = maxpool_j relu(bn2(Y1 @ Wp2))
// v13: v12 + pinned Phase-C schedule. v12 analysis: true per-SIMD MFMA
//   busy = 8192cyc/102k = 8% (MfmaUtil's 34% sums 4 SIMDs per CU-wall);
//   ~700cyc/wave-iter for 64cyc of MFMA work => each iter eats a full
//   memory latency. Theory: machine scheduler (128 arch-VGPR budget)
//   sinks ring/dbuf loads to their uses; source-level prefetch distance
//   doesn't survive. Fix (m201/m218 pattern): per step
//   {2 B-loads, 4 A-ds_reads, asm "s_waitcnt vmcnt(6) lgkmcnt(4)"
//   ["memory" clobber = placement fence], sched_barrier(0) [MFMA hoist
//   fence], 8xMFMA}. B lead=3 steps (>=L2 latency), A lead=1 step.
//   Tail peeled w/ exact counts; vm0/lgkm0 drain before each chunk
//   prologue (epilogue stores share vmcnt). Reg footprint = v12.
//   LDS = Y1 128K + HH 16K = 144 KB, 1 WG/CU, 8 waves, no K-loop barriers.
// ---------------------------------------------------------------------------

typedef __bf16 bf16x8 __attribute__((ext_vector_type(8)));
typedef __bf16 bf16x2 __attribute__((ext_vector_type(2)));
typedef float  f32x4  __attribute__((ext_vector_type(4)));
typedef float  f32x2  __attribute__((ext_vector_type(2)));
typedef float  f32x16 __attribute__((ext_vector_type(16)));

// workspace layout (bytes)
#define BP2_OFF 0u          // packed Wp2, 32x32x16 B-frags: [kstep(32)][ct(32)][l(64)]*16B = 1 MB
#define BP1_OFF 1048576u    // packed W1b (Wp1 rows 64..127): [nt(32)][kb(2)][l]*16B = 64 KB
#define MX_OFF  1114112u    // 512 f32
#define MY_OFF  1116160u
#define CB_OFF  1118208u
#define SH_OFF  1120256u
#define A2_OFF  1122304u    // 1024 f32
#define C2_OFF  1126400u

// mm2 LDS layout (bytes)
#define Y1_LDS  0           // bf16 [128 r][512 k], row stride 1024 B, off = ((c16^(r&7))<<4)
#define HH_LDS  131072      // bf16 [16 j][512 k], row stride 1024 B
#define LDS_SZ  147456      // 144 KB

__device__ __forceinline__ unsigned short f2bf(float f) {
    union { float f; unsigned u; } c; c.f = f;
    unsigned u = c.u;
    return (unsigned short)((u + 0x7fffu + ((u >> 16) & 1u)) >> 16);
}
__device__ __forceinline__ float bfbits2f(unsigned hi) {
    union { unsigned u; float f; } c; c.u = hi; return c.f;
}
__device__ __forceinline__ unsigned pk_bf16(float a, float b) {
#if __has_builtin(__builtin_amdgcn_cvt_pk_bf16_f32)
    bf16x2 p = __builtin_amdgcn_cvt_pk_bf16_f32(a, b);
    union { bf16x2 v; unsigned u; } c; c.v = p; return c.u;
#else
    return (unsigned)f2bf(a) | ((unsigned)f2bf(b) << 16);
#endif
}
// Y1 address: row r (0..127), 16-byte chunk c16 (0..63).
__device__ __forceinline__ int y1off(int r, int c16) {
    return r * 1024 + ((c16 ^ (r & 7)) << 4);
}

// ---------------------------------------------------------------------------
// prep_pack: blocks 0..255 pack Wp2 into 32x32x16 B-frag layout
// ([kstep][ct][l]); 256..271 pack W1b (16x16x32 layout for Phase A);
// 272..273 fold k-consts; 274..277 fold A2/C2. All global reads coalesced.
// 32x32x16 B-frag: lane l holds B[k=kstep*16+(l>>5)*8+j][n=ct*32+(l&31)].
// 16x16x32 B-frag: lane l holds B[k=kb*32+(l>>4)*8+j][n=nt*16+(l&15)].
// ---------------------------------------------------------------------------
__global__ __launch_bounds__(256) void prep_pack_kernel(
    const float* __restrict__ Wsp,  const float* __restrict__ bsp,
    const float* __restrict__ Wp1,  const float* __restrict__ bp1,
    const float* __restrict__ gp1,  const float* __restrict__ btp1,
    const float* __restrict__ mp1,  const float* __restrict__ vp1,
    const float* __restrict__ Wp2,  const float* __restrict__ bp2,
    const float* __restrict__ gp2,  const float* __restrict__ btp2,
    const float* __restrict__ mp2,  const float* __restrict__ vp2,
    unsigned char* __restrict__ ws)
{
    __shared__ float tile[32 * 65];
    const int blk = blockIdx.x, t = threadIdx.x;

    if (blk < 272) {
        const float* src; int ncols, kb, ng;
        if (blk < 256) { kb = blk >> 4; ng = blk & 15; src = Wp2; ncols = 1024; }
        else { int b2 = blk - 256; kb = b2 >> 3; ng = b2 & 7; src = Wp1 + 64 * 512; ncols = 512; }
        const int k0 = kb * 32, n0 = ng * 64;
        #pragma unroll
        for (int it = 0; it < 2; ++it) {
            int c = t + it * 256;
            int r = c >> 4, c4 = c & 15;
            float4 v = *(const float4*)(src + (k0 + r) * ncols + n0 + c4 * 4);
            tile[r * 65 + c4 * 4 + 0] = v.x;
            tile[r * 65 + c4 * 4 + 1] = v.y;
            tile[r * 65 + c4 * 4 + 2] = v.z;
            tile[r * 65 + c4 * 4 + 3] = v.w;
        }
        __syncthreads();
        if (blk < 256) {
            // 32x32x16 B-frags: 2 ksteps x 2 coltiles per 32x64 tile
            const int l = t & 63, ch = (t >> 6) & 1, kh = t >> 7;
            const int nl = ch * 32 + (l & 31);
            const int kl = kh * 16 + ((l >> 5) & 1) * 8;
            uint4 o;
            o.x = pk_bf16(tile[(kl + 0) * 65 + nl], tile[(kl + 1) * 65 + nl]);
            o.y = pk_bf16(tile[(kl + 2) * 65 + nl], tile[(kl + 3) * 65 + nl]);
            o.z = pk_bf16(tile[(kl + 4) * 65 + nl], tile[(kl + 5) * 65 + nl]);
            o.w = pk_bf16(tile[(kl + 6) * 65 + nl], tile[(kl + 7) * 65 + nl]);
            const int kstep = kb * 2 + kh, ct = ng * 2 + ch;
            ((uint4*)(ws + BP2_OFF))[(kstep * 32 + ct) * 64 + l] = o;
        } else {
            // 16x16x32 B-frags for Phase A (unchanged layout)
            int ntl = t >> 6, l = t & 63;
            int nl = ntl * 16 + (l & 15), kl = (l >> 4) * 8;
            uint4 o;
            o.x = pk_bf16(tile[(kl + 0) * 65 + nl], tile[(kl + 1) * 65 + nl]);
            o.y = pk_bf16(tile[(kl + 2) * 65 + nl], tile[(kl + 3) * 65 + nl]);
            o.z = pk_bf16(tile[(kl + 4) * 65 + nl], tile[(kl + 5) * 65 + nl]);
            o.w = pk_bf16(tile[(kl + 6) * 65 + nl], tile[(kl + 7) * 65 + nl]);
            ((uint4*)(ws + BP1_OFF))[((ng * 4 + ntl) * 2 + kb) * 64 + l] = o;
        }
    } else if (blk < 274) {
        int k = (blk - 272) * 256 + t;
        float a1 = gp1[k] * rsqrtf(vp1[k] + 1e-5f);
        float mx = 0.f, my = 0.f, cb = 0.f;
        for (int e = 0; e < 64; ++e) {
            float wv = Wp1[e * 512 + k];
            mx = fmaf(Wsp[e],      wv, mx);
            my = fmaf(Wsp[64 + e], wv, my);
            cb = fmaf(bsp[e],      wv, cb);
        }
        ((float*)(ws + MX_OFF))[k] = 0.05f * a1 * mx;
        ((float*)(ws + MY_OFF))[k] = 0.05f * a1 * my;
        ((float*)(ws + CB_OFF))[k] = 0.05f * a1 * cb + (bp1[k] - mp1[k]) * a1 + btp1[k];
        ((float*)(ws + SH_OFF))[k] = 0.05f * a1;
    } else {
        int n = (blk - 274) * 256 + t;
        float a = gp2[n] * rsqrtf(vp2[n] + 1e-5f);
        ((float*)(ws + A2_OFF))[n] = a;
        ((float*)(ws + C2_OFF))[n] = btp2[n] + (bp2[n] - mp2[n]) * a;
    }
}

// ---------------------------------------------------------------------------
// mm2 v13: WG = (scene s, i-half ih). 512 thr = 8 waves.
// Phase A (1 barrier): HH[16x512] via 8 MFMA/wave from h x packed W1b.
// Phase B (1 barrier): construct Y1[128x512] bf16 (MX/MY/pos from global).
// Phase C (no barriers): 32x32x16 GEMM with counted-waitcnt pinned
//   schedule; B ring-of-4 dist-3, A double-buffer dist-1; setprio.
// ---------------------------------------------------------------------------
__global__ __launch_bounds__(512, 2) void mm2_kernel(
    const float* __restrict__ hst,
    const float* __restrict__ epos,
    const unsigned char* __restrict__ ws,
    float* __restrict__ out)
{
    __shared__ __align__(16) unsigned char smem[LDS_SZ];

    const int s   = blockIdx.x >> 1;     // 256 scenes
    const int ih  = blockIdx.x & 1;      // i-half
    const int tid = threadIdx.x;
    const int w    = tid >> 6;           // 0..7
    const int l    = tid & 63;
    const int quad = l >> 4;
    const int jl   = l & 15;

    // ---- Phase A: HH via MFMA (16x16x32, unchanged) ----
    {
        union { unsigned u[4]; bf16x8 v; } afh[2];
        #pragma unroll
        for (int kb = 0; kb < 2; ++kb) {
            const float4* hp = (const float4*)(hst + (s * 16 + jl) * 64 + kb * 32 + quad * 8);
            float4 v0 = hp[0], v1 = hp[1];
            afh[kb].u[0] = pk_bf16(v0.x, v0.y);
            afh[kb].u[1] = pk_bf16(v0.z, v0.w);
            afh[kb].u[2] = pk_bf16(v1.x, v1.y);
            afh[kb].u[3] = pk_bf16(v1.z, v1.w);
        }
        const f32x4 fz = {0.f, 0.f, 0.f, 0.f};
        f32x4 acch[4] = {fz, fz, fz, fz};     // wave w -> k-cols w*64..+63
        #pragma unroll
        for (int kb = 0; kb < 2; ++kb) {
            #pragma unroll
            for (int ct = 0; ct < 4; ++ct) {
                bf16x8 bfr = *(const bf16x8*)(ws + BP1_OFF + ((((w * 4 + ct) * 2 + kb) * 64 + l) << 4));
                acch[ct] = __builtin_amdgcn_mfma_f32_16x16x32_bf16(afh[kb].v, bfr, acch[ct], 0, 0, 0);
            }
        }
        const float* SHg = (const float*)(ws + SH_OFF);
        const float* CBg = (const float*)(ws + CB_OFF);
        #pragma unroll
        for (int ct = 0; ct < 4; ++ct) {
            int col = (w * 4 + ct) * 16 + jl;        // k index
            float sh = SHg[col], cb = CBg[col];
            #pragma unroll
            for (int reg = 0; reg < 4; ++reg) {
                int j = quad * 4 + reg;
                float hv = fmaf(acch[ct][reg], sh, cb);
                *(unsigned short*)(smem + HH_LDS + j * 1024 + col * 2) = f2bf(hv);
            }
        }
    }
    __syncthreads();

    // ---- Phase B: construct Y1 (bf16, swizzled); MX/MY/pos from global ----
    {
        const int i2 = tid >> 8;           // 0..1  (4 i each)
        const int j  = (tid >> 4) & 15;
        const int kc = tid & 15;           // k0 = kc*32
        float rx[4], ry[4];
        float pjx = epos[s * 32 + j * 2], pjy = epos[s * 32 + j * 2 + 1];
        #pragma unroll
        for (int ii = 0; ii < 4; ++ii) {
            int ig_ = ih * 8 + i2 * 4 + ii;
            rx[ii] = pjx - epos[s * 32 + ig_ * 2];
            ry[ii] = pjy - epos[s * 32 + ig_ * 2 + 1];
        }
        const f32x2 zero2 = {0.f, 0.f};
        #pragma unroll
        for (int kk = 0; kk < 4; ++kk) {
            int k = kc * 32 + kk * 8;
            uint4 hh8 = *(const uint4*)(smem + HH_LDS + j * 1024 + k * 2);
            f32x4 mx0 = *(const f32x4*)(ws + MX_OFF + k * 4);
            f32x4 mx1 = *(const f32x4*)(ws + MX_OFF + k * 4 + 16);
            f32x4 my0 = *(const f32x4*)(ws + MY_OFF + k * 4);
            f32x4 my1 = *(const f32x4*)(ws + MY_OFF + k * 4 + 16);
            f32x2 mxp[4] = { {mx0[0],mx0[1]}, {mx0[2],mx0[3]}, {mx1[0],mx1[1]}, {mx1[2],mx1[3]} };
            f32x2 myp[4] = { {my0[0],my0[1]}, {my0[2],my0[3]}, {my1[0],my1[1]}, {my1[2],my1[3]} };
            f32x2 hhp[4];
            hhp[0][0] = bfbits2f(hh8.x << 16); hhp[0][1] = bfbits2f(hh8.x & 0xffff0000u);
            hhp[1][0] = bfbits2f(hh8.y << 16); hhp[1][1] = bfbits2f(hh8.y & 0xffff0000u);
            hhp[2][0] = bfbits2f(hh8.z << 16); hhp[2][1] = bfbits2f(hh8.z & 0xffff0000u);
            hhp[3][0] = bfbits2f(hh8.w << 16); hhp[3][1] = bfbits2f(hh8.w & 0xffff0000u);
            #pragma unroll
            for (int ii = 0; ii < 4; ++ii) {
                f32x2 rx2 = { rx[ii], rx[ii] };
                f32x2 ry2 = { ry[ii], ry[ii] };
                uint4 o;
                unsigned uu[4];
                #pragma unroll
                for (int p = 0; p < 4; ++p) {
                    f32x2 tt = __builtin_elementwise_fma(ry2, myp[p], hhp[p]);
                    tt = __builtin_elementwise_fma(rx2, mxp[p], tt);
                    tt = __builtin_elementwise_max(tt, zero2);
                    uu[p] = pk_bf16(tt[0], tt[1]);
                }
                o.x = uu[0]; o.y = uu[1]; o.z = uu[2]; o.w = uu[3];
                int r = (i2 * 4 + ii) * 16 + j;
                *(uint4*)(smem + Y1_LDS + y1off(r, kc * 4 + kk)) = o;
            }
        }
    }
    __syncthreads();

    // ---- Phase C: 32x32x16 GEMM, counted-waitcnt pinned schedule ----
    {
        const int lane31 = l & 31;           // = A-frag m within 32-row tile, = C col
        const int hi = l >> 5;               // k-half of A/B frags; C row group
        const int sr = lane31 & 7;           // r&7 for all rowtiles (rows rt*32+lane31)
        const float* A2 = (const float*)(ws + A2_OFF);
        const float* C2 = (const float*)(ws + C2_OFF);

        // addr(rt,kstep) = (av[rt] + (kstep>>2)*128) ^ ((kstep&3)<<5)
        int av[4];
        #pragma unroll
        for (int rt = 0; rt < 4; ++rt)
            av[rt] = Y1_LDS + (rt * 32 + lane31) * 1024 + ((hi ^ sr) << 4);

        const f32x16 fz16 = {0.f,0.f,0.f,0.f,0.f,0.f,0.f,0.f,
                             0.f,0.f,0.f,0.f,0.f,0.f,0.f,0.f};

        #pragma unroll 1
        for (int chunk = 0; chunk < 2; ++chunk) {
            const int ctbase = w * 4 + chunk * 2;
            const unsigned char* bp = ws + BP2_OFF + (ctbase << 10) + (l << 4);
            // B addr = bp + kstep*32768 + c*1024

            f32x16 acc[4][2];
            #pragma unroll
            for (int rt = 0; rt < 4; ++rt) { acc[rt][0] = fz16; acc[rt][1] = fz16; }

            bf16x8 a0[4], a1[4];   // A double-buffer (dist-1)
            bf16x8 br[4][2];       // B ring-of-4, slot = kstep & 3 (dist-3)

            auto ldA = [&](bf16x8* dst, int add, int xorv) {
                #pragma unroll
                for (int rt = 0; rt < 4; ++rt)
                    dst[rt] = *(const bf16x8*)(smem + ((av[rt] + add) ^ xorv));
            };
            auto ldB = [&](bf16x8* slot, const unsigned char* base, int off) {
                slot[0] = *(const bf16x8*)(base + off);
                slot[1] = *(const bf16x8*)(base + off + 1024);
            };
            auto mfma8 = [&](const bf16x8* a, const bf16x8* b) {
                __builtin_amdgcn_s_setprio(1);
                #pragma unroll
                for (int c = 0; c < 2; ++c)
                    #pragma unroll
                    for (int rt = 0; rt < 4; ++rt)
                        acc[rt][c] = __builtin_amdgcn_mfma_f32_32x32x16_bf16(
                            a[rt], b[c], acc[rt][c], 0, 0, 0);
                __builtin_amdgcn_s_setprio(0);
            };

            // drain (prior chunk's epilogue stores share vmcnt; clean baseline)
            asm volatile("s_waitcnt vmcnt(0) lgkmcnt(0)" ::: "memory");

            // prologue: B ksteps 0,1,2 (6 vm); A kstep 0 (4 lgkm)
            ldB(br[0], bp, 0);
            ldB(br[1], bp, 32768);
            ldB(br[2], bp, 65536);
            ldA(a0, 0, 0);

            #pragma unroll 1
            for (int kq = 0; kq < 7; ++kq) {
                const unsigned char* bq = bp + kq * 131072;
                const int ka = kq * 128;
                // m=0: kstep 4kq. issue B(+3)->slot3, A(+1)->a1; wait; mfma
                ldB(br[3], bq, 98304);
                ldA(a1, ka, 32);
                asm volatile("s_waitcnt vmcnt(6) lgkmcnt(4)" ::: "memory");
                __builtin_amdgcn_sched_barrier(0);
                mfma8(a0, br[0]);
                // m=1: B->slot0 (4kq+4), A->a0 (4kq+2)
                ldB(br[0], bq, 131072);
                ldA(a0, ka, 64);
                asm volatile("s_waitcnt vmcnt(6) lgkmcnt(4)" ::: "memory");
                __builtin_amdgcn_sched_barrier(0);
                mfma8(a1, br[1]);
                // m=2: B->slot1 (4kq+5), A->a1 (4kq+3)
                ldB(br[1], bq, 163840);
                ldA(a1, ka, 96);
                asm volatile("s_waitcnt vmcnt(6) lgkmcnt(4)" ::: "memory");
                __builtin_amdgcn_sched_barrier(0);
                mfma8(a0, br[2]);
                // m=3: B->slot2 (4kq+6), A->a0 (4(kq+1))
                ldB(br[2], bq, 196608);
                ldA(a0, ka + 128, 0);
                asm volatile("s_waitcnt vmcnt(6) lgkmcnt(4)" ::: "memory");
                __builtin_amdgcn_sched_barrier(0);
                mfma8(a1, br[3]);
            }
            // kq=7 tail: ksteps 28..31, exact counts
            {
                const unsigned char* bq = bp + 7 * 131072;
                const int ka = 7 * 128;
                // k=28: B(31)->slot3, A(29)->a1
                ldB(br[3], bq, 98304);
                ldA(a1, ka, 32);
                asm volatile("s_waitcnt vmcnt(6) lgkmcnt(4)" ::: "memory");
                __builtin_amdgcn_sched_barrier(0);
                mfma8(a0, br[0]);
                // k=29: A(30)->a0; no B
                ldA(a0, ka, 64);
                asm volatile("s_waitcnt vmcnt(4) lgkmcnt(4)" ::: "memory");
                __builtin_amdgcn_sched_barrier(0);
                mfma8(a1, br[1]);
                // k=30: A(31)->a1; no B
                ldA(a1, ka, 96);
                asm volatile("s_waitcnt vmcnt(2) lgkmcnt(4)" ::: "memory");
                __builtin_amdgcn_sched_barrier(0);
                mfma8(a0, br[2]);
                // k=31: no issues
                asm volatile("s_waitcnt vmcnt(0) lgkmcnt(0)" ::: "memory");
                __builtin_amdgcn_sched_barrier(0);
                mfma8(a1, br[3]);
            }

            // epilogue: bn2 + relu, maxpool over j, store fp32.
            // C/D 32x32: col = lane&31, row = (reg&3)+8*(reg>>2)+4*hi.
            // regs 0..7  -> tile rows 0..15  (i_local = rt*2)
            // regs 8..15 -> tile rows 16..31 (i_local = rt*2+1)
            // full 16-j max = max(own 8 regs, shfl_xor 32).
            #pragma unroll
            for (int c = 0; c < 2; ++c) {
                const int col = (ctbase + c) * 32 + lane31;
                const float a2 = A2[col], c2v = C2[col];
                #pragma unroll
                for (int rt = 0; rt < 4; ++rt) {
                    float mv[2];
                    #pragma unroll
                    for (int hg = 0; hg < 2; ++hg) {
                        float v0 = fmaxf(fmaf(acc[rt][c][hg * 8 + 0], a2, c2v), 0.f);
                        float v1 = fmaxf(fmaf(acc[rt][c][hg * 8 + 1], a2, c2v), 0.f);
                        float v2 = fmaxf(fmaf(acc[rt][c][hg * 8 + 2], a2, c2v), 0.f);
                        float v3 = fmaxf(fmaf(acc[rt][c][hg * 8 + 3], a2, c2v), 0.f);
                        float v4 = fmaxf(fmaf(acc[rt][c][hg * 8 + 4], a2, c2v), 0.f);
                        float v5 = fmaxf(fmaf(acc[rt][c][hg * 8 + 5], a2, c2v), 0.f);
                        float v6 = fmaxf(fmaf(acc[rt][c][hg * 8 + 6], a2, c2v), 0.f);
                        float v7 = fmaxf(fmaf(acc[rt][c][hg * 8 + 7], a2, c2v), 0.f);
                        float m = fmaxf(fmaxf(fmaxf(v0, v1), fmaxf(v2, v3)),
                                        fmaxf(fmaxf(v4, v5), fmaxf(v6, v7)));
                        mv[hg] = fmaxf(m, __shfl_xor(m, 32, 64));
                    }
                    const int iloc = rt * 2 + hi;       // hi=0 stores even i, hi=1 odd
                    const float vout = hi ? mv[1] : mv[0];
                    const int orow = s * 16 + ih * 8 + iloc;
                    __builtin_nontemporal_store(vout, &out[orow * 1024 + col]);
                }
            }
        }
    }
}

extern "C" void kernel_launch(void* const* d_in, const int* in_sizes, int n_in,
                              void* d_out, int out_size, void* d_ws, size_t ws_size,
                              hipStream_t stream) {
    const float* hst  = (const float*)d_in[0];
    const float* epos = (const float*)d_in[1];
    const float* Wsp  = (const float*)d_in[4];
    const float* bsp  = (const float*)d_in[5];
    const float* Wp1  = (const float*)d_in[20];
    const float* bp1  = (const float*)d_in[21];
    const float* gp1  = (const float*)d_in[22];
    const float* btp1 = (const float*)d_in[23];
    const float* mp1  = (const float*)d_in[24];
    const float* vp1  = (const float*)d_in[25];
    const float* Wp2  = (const float*)d_in[26];
    const float* bp2  = (const float*)d_in[27];
    const float* gp2  = (const float*)d_in[28];
    const float* btp2 = (const float*)d_in[29];
    const float* mp2  = (const float*)d_in[30];
    const float* vp2  = (const float*)d_in[31];
    unsigned char* ws = (unsigned char*)d_ws;
    float* out = (float*)d_out;

    // 256 (Wp2 pack) + 16 (W1b pack) + 2 (k-consts) + 4 (A2/C2) = 278 blocks
    prep_pack_kernel<<<278, 256, 0, stream>>>(Wsp, bsp, Wp1, bp1, gp1, btp1, mp1, vp1,
                                              Wp2, bp2, gp2, btp2, mp2, vp2, ws);
    // 256 scenes x 2 i-halves, 512 threads (8 waves)
    mm2_kernel<<<512, 512, 0, stream>>>(hst, epos, ws, out);
}

// Round 4
// 188.272 us; speedup vs baseline: 1.3097x; 1.0150x over previous
//
#include <hip/hip_runtime.h>
#include <hip/hip_bf16.h>
#include <stdint.h>

// ---------------------------------------------------------------------------
// E=64 H=64 PRE1=512 BNK=1024 S=256 P=16 B=4096. Attention branch dead
// (softmax over size-1 axis == 1). Decomposition (rel is rank-2):
//   Z1[s,i,j,k] = rx*MX[k] + ry*MY[k] + HH[16s+j][k];  Y1 = relu(Z1)
//   out = maxpool_j relu(bn2(Y1 @ Wp2))
// v14: v13 + attributable-overhead removal.
//   (1) Phase B remap: thread chunk = kk*16+kc (k = kk*128+kc*8) -> Y1
//       writes and HH reads go stride-16B per 8-lane group = conflict-free
//       (v13: stride-64B = 4-way; 6.09M conflict cyc = 14% of wall).
//   (2) Phase C: continuous 64-step B-ring across the chunk boundary (no
//       vmcnt(0) drain): chunk1 ksteps 0..2 issued during chunk0 tail;
//       boundary waits vmcnt(18) count the 8 epilogue stores + 4 a2c2
//       loads (vmcnt retires in issue order). A2/C2 preloaded pre-loop.
//   (3) setprio removed (m190: negative for lockstep GEMM).
//   (4) B loads nontemporal (protect BP2 L2 residency from out-stream).
//   (5) prep k-consts spread over 8 blocks (4-way e-split + LDS reduce).
//   Regs ~120 arch + 128 acc = ~248 <= 256 (2 waves/SIMD budget).
//   LDS = Y1 128K + HH 16K = 144 KB, 1 WG/CU, 8 waves, no K-loop barriers.
// ---------------------------------------------------------------------------

typedef __bf16 bf16x8 __attribute__((ext_vector_type(8)));
typedef __bf16 bf16x2 __attribute__((ext_vector_type(2)));
typedef float  f32x4  __attribute__((ext_vector_type(4)));
typedef float  f32x2  __attribute__((ext_vector_type(2)));
typedef float  f32x16 __attribute__((ext_vector_type(16)));

// workspace layout (bytes)
#define BP2_OFF 0u          // packed Wp2, 32x32x16 B-frags: [kstep(32)][ct(32)][l(64)]*16B = 1 MB
#define BP1_OFF 1048576u    // packed W1b (Wp1 rows 64..127): [nt(32)][kb(2)][l]*16B = 64 KB
#define MX_OFF  1114112u    // 512 f32
#define MY_OFF  1116160u
#define CB_OFF  1118208u
#define SH_OFF  1120256u
#define A2_OFF  1122304u    // 1024 f32
#define C2_OFF  1126400u

// mm2 LDS layout (bytes)
#define Y1_LDS  0           // bf16 [128 r][512 k], row stride 1024 B, off = ((c16^(r&7))<<4)
#define HH_LDS  131072      // bf16 [16 j][512 k], row stride 1024 B
#define LDS_SZ  147456      // 144 KB

#define WAITCNT(S) do { asm volatile("s_waitcnt " S ::: "memory"); \
                        __builtin_amdgcn_sched_barrier(0); } while (0)

__device__ __forceinline__ unsigned short f2bf(float f) {
    union { float f; unsigned u; } c; c.f = f;
    unsigned u = c.u;
    return (unsigned short)((u + 0x7fffu + ((u >> 16) & 1u)) >> 16);
}
__device__ __forceinline__ float bfbits2f(unsigned hi) {
    union { unsigned u; float f; } c; c.u = hi; return c.f;
}
__device__ __forceinline__ unsigned pk_bf16(float a, float b) {
#if __has_builtin(__builtin_amdgcn_cvt_pk_bf16_f32)
    bf16x2 p = __builtin_amdgcn_cvt_pk_bf16_f32(a, b);
    union { bf16x2 v; unsigned u; } c; c.v = p; return c.u;
#else
    return (unsigned)f2bf(a) | ((unsigned)f2bf(b) << 16);
#endif
}
// Y1 address: row r (0..127), 16-byte chunk c16 (0..63).
__device__ __forceinline__ int y1off(int r, int c16) {
    return r * 1024 + ((c16 ^ (r & 7)) << 4);
}

// ---------------------------------------------------------------------------
// prep_pack: blocks 0..255 pack Wp2 into 32x32x16 B-frag layout
// ([kstep][ct][l]); 256..271 pack W1b (16x16x32 layout for Phase A);
// 272..279 fold k-consts (64 k each, 4-way e-split + LDS reduce);
// 280..283 fold A2/C2. All global reads coalesced.
// 32x32x16 B-frag: lane l holds B[k=kstep*16+(l>>5)*8+j][n=ct*32+(l&31)].
// 16x16x32 B-frag: lane l holds B[k=kb*32+(l>>4)*8+j][n=nt*16+(l&15)].
// ---------------------------------------------------------------------------
__global__ __launch_bounds__(256) void prep_pack_kernel(
    const float* __restrict__ Wsp,  const float* __restrict__ bsp,
    const float* __restrict__ Wp1,  const float* __restrict__ bp1,
    const float* __restrict__ gp1,  const float* __restrict__ btp1,
    const float* __restrict__ mp1,  const float* __restrict__ vp1,
    const float* __restrict__ Wp2,  const float* __restrict__ bp2,
    const float* __restrict__ gp2,  const float* __restrict__ btp2,
    const float* __restrict__ mp2,  const float* __restrict__ vp2,
    unsigned char* __restrict__ ws)
{
    __shared__ float tile[32 * 65];
    __shared__ float part[3][4][64];
    const int blk = blockIdx.x, t = threadIdx.x;

    if (blk < 272) {
        const float* src; int ncols, kb, ng;
        if (blk < 256) { kb = blk >> 4; ng = blk & 15; src = Wp2; ncols = 1024; }
        else { int b2 = blk - 256; kb = b2 >> 3; ng = b2 & 7; src = Wp1 + 64 * 512; ncols = 512; }
        const int k0 = kb * 32, n0 = ng * 64;
        #pragma unroll
        for (int it = 0; it < 2; ++it) {
            int c = t + it * 256;
            int r = c >> 4, c4 = c & 15;
            float4 v = *(const float4*)(src + (k0 + r) * ncols + n0 + c4 * 4);
            tile[r * 65 + c4 * 4 + 0] = v.x;
            tile[r * 65 + c4 * 4 + 1] = v.y;
            tile[r * 65 + c4 * 4 + 2] = v.z;
            tile[r * 65 + c4 * 4 + 3] = v.w;
        }
        __syncthreads();
        if (blk < 256) {
            // 32x32x16 B-frags: 2 ksteps x 2 coltiles per 32x64 tile
            const int l = t & 63, ch = (t >> 6) & 1, kh = t >> 7;
            const int nl = ch * 32 + (l & 31);
            const int kl = kh * 16 + ((l >> 5) & 1) * 8;
            uint4 o;
            o.x = pk_bf16(tile[(kl + 0) * 65 + nl], tile[(kl + 1) * 65 + nl]);
            o.y = pk_bf16(tile[(kl + 2) * 65 + nl], tile[(kl + 3) * 65 + nl]);
            o.z = pk_bf16(tile[(kl + 4) * 65 + nl], tile[(kl + 5) * 65 + nl]);
            o.w = pk_bf16(tile[(kl + 6) * 65 + nl], tile[(kl + 7) * 65 + nl]);
            const int kstep = kb * 2 + kh, ct = ng * 2 + ch;
            ((uint4*)(ws + BP2_OFF))[(kstep * 32 + ct) * 64 + l] = o;
        } else {
            // 16x16x32 B-frags for Phase A (unchanged layout)
            int ntl = t >> 6, l = t & 63;
            int nl = ntl * 16 + (l & 15), kl = (l >> 4) * 8;
            uint4 o;
            o.x = pk_bf16(tile[(kl + 0) * 65 + nl], tile[(kl + 1) * 65 + nl]);
            o.y = pk_bf16(tile[(kl + 2) * 65 + nl], tile[(kl + 3) * 65 + nl]);
            o.z = pk_bf16(tile[(kl + 4) * 65 + nl], tile[(kl + 5) * 65 + nl]);
            o.w = pk_bf16(tile[(kl + 6) * 65 + nl], tile[(kl + 7) * 65 + nl]);
            ((uint4*)(ws + BP1_OFF))[((ng * 4 + ntl) * 2 + kb) * 64 + l] = o;
        }
    } else if (blk < 280) {
        // k-consts: 64 k per block, 4 threads per k (16 e each), LDS reduce
        const int kk = t & 63, eq = t >> 6;
        const int k = (blk - 272) * 64 + kk;
        float mx = 0.f, my = 0.f, cb = 0.f;
        #pragma unroll
        for (int e2 = 0; e2 < 16; ++e2) {
            int e = eq * 16 + e2;
            float wv = Wp1[e * 512 + k];
            mx = fmaf(Wsp[e],      wv, mx);
            my = fmaf(Wsp[64 + e], wv, my);
            cb = fmaf(bsp[e],      wv, cb);
        }
        part[0][eq][kk] = mx; part[1][eq][kk] = my; part[2][eq][kk] = cb;
        __syncthreads();
        if (t < 64) {
            const int k2 = (blk - 272) * 64 + t;
            float mxs = part[0][0][t] + part[0][1][t] + part[0][2][t] + part[0][3][t];
            float mys = part[1][0][t] + part[1][1][t] + part[1][2][t] + part[1][3][t];
            float cbs = part[2][0][t] + part[2][1][t] + part[2][2][t] + part[2][3][t];
            float a1 = gp1[k2] * rsqrtf(vp1[k2] + 1e-5f);
            ((float*)(ws + MX_OFF))[k2] = 0.05f * a1 * mxs;
            ((float*)(ws + MY_OFF))[k2] = 0.05f * a1 * mys;
            ((float*)(ws + CB_OFF))[k2] = 0.05f * a1 * cbs + (bp1[k2] - mp1[k2]) * a1 + btp1[k2];
            ((float*)(ws + SH_OFF))[k2] = 0.05f * a1;
        }
    } else {
        int n = (blk - 280) * 256 + t;
        float a = gp2[n] * rsqrtf(vp2[n] + 1e-5f);
        ((float*)(ws + A2_OFF))[n] = a;
        ((float*)(ws + C2_OFF))[n] = btp2[n] + (bp2[n] - mp2[n]) * a;
    }
}

// ---------------------------------------------------------------------------
// mm2 v14: WG = (scene s, i-half ih). 512 thr = 8 waves.
// Phase A (1 barrier): HH[16x512] via 8 MFMA/wave from h x packed W1b.
// Phase B (1 barrier): construct Y1[128x512] bf16 (conflict-free mapping).
// Phase C (no barriers): 32x32x16 GEMM, counted-waitcnt pinned schedule,
//   continuous 64-step B-ring (dist-3) across the chunk boundary.
// ---------------------------------------------------------------------------
__global__ __launch_bounds__(512, 2) void mm2_kernel(
    const float* __restrict__ hst,
    const float* __restrict__ epos,
    const unsigned char* __restrict__ ws,
    float* __restrict__ out)
{
    __shared__ __align__(16) unsigned char smem[LDS_SZ];

    const int s   = blockIdx.x >> 1;     // 256 scenes
    const int ih  = blockIdx.x & 1;      // i-half
    const int tid = threadIdx.x;
    const int w    = tid >> 6;           // 0..7
    const int l    = tid & 63;
    const int quad = l >> 4;
    const int jl   = l & 15;

    // ---- Phase A: HH via MFMA (16x16x32, unchanged) ----
    {
        union { unsigned u[4]; bf16x8 v; } afh[2];
        #pragma unroll
        for (int kb = 0; kb < 2; ++kb) {
            const float4* hp = (const float4*)(hst + (s * 16 + jl) * 64 + kb * 32 + quad * 8);
            float4 v0 = hp[0], v1 = hp[1];
            afh[kb].u[0] = pk_bf16(v0.x, v0.y);
            afh[kb].u[1] = pk_bf16(v0.z, v0.w);
            afh[kb].u[2] = pk_bf16(v1.x, v1.y);
            afh[kb].u[3] = pk_bf16(v1.z, v1.w);
        }
        const f32x4 fz = {0.f, 0.f, 0.f, 0.f};
        f32x4 acch[4] = {fz, fz, fz, fz};     // wave w -> k-cols w*64..+63
        #pragma unroll
        for (int kb = 0; kb < 2; ++kb) {
            #pragma unroll
            for (int ct = 0; ct < 4; ++ct) {
                bf16x8 bfr = *(const bf16x8*)(ws + BP1_OFF + ((((w * 4 + ct) * 2 + kb) * 64 + l) << 4));
                acch[ct] = __builtin_amdgcn_mfma_f32_16x16x32_bf16(afh[kb].v, bfr, acch[ct], 0, 0, 0);
            }
        }
        const float* SHg = (const float*)(ws + SH_OFF);
        const float* CBg = (const float*)(ws + CB_OFF);
        #pragma unroll
        for (int ct = 0; ct < 4; ++ct) {
            int col = (w * 4 + ct) * 16 + jl;        // k index
            float sh = SHg[col], cb = CBg[col];
            #pragma unroll
            for (int reg = 0; reg < 4; ++reg) {
                int j = quad * 4 + reg;
                float hv = fmaf(acch[ct][reg], sh, cb);
                *(unsigned short*)(smem + HH_LDS + j * 1024 + col * 2) = f2bf(hv);
            }
        }
    }
    __syncthreads();

    // ---- Phase B: construct Y1 (bf16, swizzled). Conflict-free mapping:
    //      thread (kc,kk) owns chunk c16 = kk*16+kc (k = kk*128+kc*8), so
    //      8-lane groups write/read at 16B stride (all 32 banks). ----
    {
        const int i2 = tid >> 8;           // 0..1  (4 i each)
        const int j  = (tid >> 4) & 15;
        const int kc = tid & 15;
        float rx[4], ry[4];
        float pjx = epos[s * 32 + j * 2], pjy = epos[s * 32 + j * 2 + 1];
        #pragma unroll
        for (int ii = 0; ii < 4; ++ii) {
            int ig_ = ih * 8 + i2 * 4 + ii;
            rx[ii] = pjx - epos[s * 32 + ig_ * 2];
            ry[ii] = pjy - epos[s * 32 + ig_ * 2 + 1];
        }
        const f32x2 zero2 = {0.f, 0.f};
        #pragma unroll
        for (int kk = 0; kk < 4; ++kk) {
            int c16 = kk * 16 + kc;
            int k = c16 * 8;               // = kk*128 + kc*8
            uint4 hh8 = *(const uint4*)(smem + HH_LDS + j * 1024 + k * 2);
            f32x4 mx0 = *(const f32x4*)(ws + MX_OFF + k * 4);
            f32x4 mx1 = *(const f32x4*)(ws + MX_OFF + k * 4 + 16);
            f32x4 my0 = *(const f32x4*)(ws + MY_OFF + k * 4);
            f32x4 my1 = *(const f32x4*)(ws + MY_OFF + k * 4 + 16);
            f32x2 mxp[4] = { {mx0[0],mx0[1]}, {mx0[2],mx0[3]}, {mx1[0],mx1[1]}, {mx1[2],mx1[3]} };
            f32x2 myp[4] = { {my0[0],my0[1]}, {my0[2],my0[3]}, {my1[0],my1[1]}, {my1[2],my1[3]} };
            f32x2 hhp[4];
            hhp[0][0] = bfbits2f(hh8.x << 16); hhp[0][1] = bfbits2f(hh8.x & 0xffff0000u);
            hhp[1][0] = bfbits2f(hh8.y << 16); hhp[1][1] = bfbits2f(hh8.y & 0xffff0000u);
            hhp[2][0] = bfbits2f(hh8.z << 16); hhp[2][1] = bfbits2f(hh8.z & 0xffff0000u);
            hhp[3][0] = bfbits2f(hh8.w << 16); hhp[3][1] = bfbits2f(hh8.w & 0xffff0000u);
            #pragma unroll
            for (int ii = 0; ii < 4; ++ii) {
                f32x2 rx2 = { rx[ii], rx[ii] };
                f32x2 ry2 = { ry[ii], ry[ii] };
                uint4 o;
                unsigned uu[4];
                #pragma unroll
                for (int p = 0; p < 4; ++p) {
                    f32x2 tt = __builtin_elementwise_fma(ry2, myp[p], hhp[p]);
                    tt = __builtin_elementwise_fma(rx2, mxp[p], tt);
                    tt = __builtin_elementwise_max(tt, zero2);
                    uu[p] = pk_bf16(tt[0], tt[1]);
                }
                o.x = uu[0]; o.y = uu[1]; o.z = uu[2]; o.w = uu[3];
                int r = (i2 * 4 + ii) * 16 + j;
                *(uint4*)(smem + Y1_LDS + y1off(r, c16)) = o;
            }
        }
    }
    __syncthreads();

    // ---- Phase C: 32x32x16 GEMM, continuous 64-step pinned schedule ----
    {
        const int lane31 = l & 31;           // = A-frag m within 32-row tile, = C col
        const int hi = l >> 5;               // k-half of A/B frags; C row group
        const int sr = lane31 & 7;           // r&7 for all rowtiles (rows rt*32+lane31)
        const float* A2 = (const float*)(ws + A2_OFF);
        const float* C2 = (const float*)(ws + C2_OFF);

        // addr(rt,kstep) = (av[rt] + (kstep>>2)*128) ^ ((kstep&3)<<5)
        int av[4];
        #pragma unroll
        for (int rt = 0; rt < 4; ++rt)
            av[rt] = Y1_LDS + (rt * 32 + lane31) * 1024 + ((hi ^ sr) << 4);

        const f32x16 fz16 = {0.f,0.f,0.f,0.f,0.f,0.f,0.f,0.f,
                             0.f,0.f,0.f,0.f,0.f,0.f,0.f,0.f};

        const int ctb0 = w * 4;              // chunk0 coltiles ctb0, ctb0+1
        const unsigned char* bp = ws + BP2_OFF + (ctb0 << 10) + (l << 4);
        // B addr(chunk, kstep, c) = bp + chunk*2048 + kstep*32768 + c*1024

        f32x16 acc[4][2];
        bf16x8 a0[4], a1[4];   // A double-buffer (dist-1)
        bf16x8 br[4][2];       // B ring-of-4, slot = vkstep & 3 (dist-3)
        float a2v[2], c2v[2];

        auto ldA = [&](bf16x8* dst, int add, int xorv) {
            #pragma unroll
            for (int rt = 0; rt < 4; ++rt)
                dst[rt] = *(const bf16x8*)(smem + ((av[rt] + add) ^ xorv));
        };
        auto ldB = [&](bf16x8* slot, const unsigned char* p) {
            slot[0] = __builtin_nontemporal_load((const bf16x8*)p);
            slot[1] = __builtin_nontemporal_load((const bf16x8*)(p + 1024));
        };
        auto mfma8 = [&](const bf16x8* a, const bf16x8* b) {
            #pragma unroll
            for (int c = 0; c < 2; ++c)
                #pragma unroll
                for (int rt = 0; rt < 4; ++rt)
                    acc[rt][c] = __builtin_amdgcn_mfma_f32_32x32x16_bf16(
                        a[rt], b[c], acc[rt][c], 0, 0, 0);
        };
        // epilogue: bn2 + relu, maxpool over j, store fp32. 8 stores.
        // C/D 32x32: col = lane&31, row = (reg&3)+8*(reg>>2)+4*hi.
        auto epilogue = [&](int ctb) {
            #pragma unroll
            for (int c = 0; c < 2; ++c) {
                const int col = (ctb + c) * 32 + lane31;
                const float a2 = a2v[c], c2 = c2v[c];
                #pragma unroll
                for (int rt = 0; rt < 4; ++rt) {
                    float mv[2];
                    #pragma unroll
                    for (int hg = 0; hg < 2; ++hg) {
                        float v0 = fmaxf(fmaf(acc[rt][c][hg * 8 + 0], a2, c2), 0.f);
                        float v1 = fmaxf(fmaf(acc[rt][c][hg * 8 + 1], a2, c2), 0.f);
                        float v2 = fmaxf(fmaf(acc[rt][c][hg * 8 + 2], a2, c2), 0.f);
                        float v3 = fmaxf(fmaf(acc[rt][c][hg * 8 + 3], a2, c2), 0.f);
                        float v4 = fmaxf(fmaf(acc[rt][c][hg * 8 + 4], a2, c2), 0.f);
                        float v5 = fmaxf(fmaf(acc[rt][c][hg * 8 + 5], a2, c2), 0.f);
                        float v6 = fmaxf(fmaf(acc[rt][c][hg * 8 + 6], a2, c2), 0.f);
                        float v7 = fmaxf(fmaf(acc[rt][c][hg * 8 + 7], a2, c2), 0.f);
                        float m = fmaxf(fmaxf(fmaxf(v0, v1), fmaxf(v2, v3)),
                                        fmaxf(fmaxf(v4, v5), fmaxf(v6, v7)));
                        mv[hg] = fmaxf(m, __shfl_xor(m, 32, 64));
                    }
                    const int iloc = rt * 2 + hi;
                    const float vout = hi ? mv[1] : mv[0];
                    const int orow = s * 16 + ih * 8 + iloc;
                    __builtin_nontemporal_store(vout, &out[orow * 1024 + col]);
                }
            }
        };

        // prologue (chunk0): a2c2 (4 loads), B k0,1,2 (6 loads), A k0 (4 ds)
        a2v[0] = A2[ctb0 * 32 + lane31];        a2v[1] = A2[(ctb0 + 1) * 32 + lane31];
        c2v[0] = C2[ctb0 * 32 + lane31];        c2v[1] = C2[(ctb0 + 1) * 32 + lane31];
        #pragma unroll
        for (int rt = 0; rt < 4; ++rt) { acc[rt][0] = fz16; acc[rt][1] = fz16; }
        ldB(br[0], bp);
        ldB(br[1], bp + 32768);
        ldB(br[2], bp + 65536);
        ldA(a0, 0, 0);

        // chunk0 kq 0..6 (vk 0..27)
        #pragma unroll 1
        for (int kq = 0; kq < 7; ++kq) {
            const unsigned char* bq = bp + kq * 131072;
            const int ka = kq * 128;
            ldB(br[3], bq + 98304);  ldA(a1, ka, 32);
            WAITCNT("vmcnt(6) lgkmcnt(4)");  mfma8(a0, br[0]);
            ldB(br[0], bq + 131072); ldA(a0, ka, 64);
            WAITCNT("vmcnt(6) lgkmcnt(4)");  mfma8(a1, br[1]);
            ldB(br[1], bq + 163840); ldA(a1, ka, 96);
            WAITCNT("vmcnt(6) lgkmcnt(4)");  mfma8(a0, br[2]);
            ldB(br[2], bq + 196608); ldA(a0, ka + 128, 0);
            WAITCNT("vmcnt(6) lgkmcnt(4)");  mfma8(a1, br[3]);
        }
        // kq7 (vk 28..31): B prefetch rolls into chunk1 ksteps 0..2
        {
            const unsigned char* bq = bp + 7 * 131072;
            const unsigned char* b1 = bp + 2048;
            const int ka = 7 * 128;
            ldB(br[3], bq + 98304);  ldA(a1, ka, 32);
            WAITCNT("vmcnt(6) lgkmcnt(4)");  mfma8(a0, br[0]);
            ldB(br[0], b1);          ldA(a0, ka, 64);
            WAITCNT("vmcnt(6) lgkmcnt(4)");  mfma8(a1, br[1]);
            ldB(br[1], b1 + 32768);  ldA(a1, ka, 96);
            WAITCNT("vmcnt(6) lgkmcnt(4)");  mfma8(a0, br[2]);
            ldB(br[2], b1 + 65536);  ldA(a0, 0, 0);   // A for chunk1 k0
            WAITCNT("vmcnt(6) lgkmcnt(4)");  mfma8(a1, br[3]);
        }
        // boundary: epilogue chunk0 (8 stores), a2c2 chunk1 (4 loads), reset acc
        __builtin_amdgcn_sched_barrier(0);
        epilogue(ctb0);
        a2v[0] = A2[(ctb0 + 2) * 32 + lane31];  a2v[1] = A2[(ctb0 + 3) * 32 + lane31];
        c2v[0] = C2[(ctb0 + 2) * 32 + lane31];  c2v[1] = C2[(ctb0 + 3) * 32 + lane31];
        #pragma unroll
        for (int rt = 0; rt < 4; ++rt) { acc[rt][0] = fz16; acc[rt][1] = fz16; }
        __builtin_amdgcn_sched_barrier(0);
        // chunk1 kq8 (vk 32..35): first 3 waits count 8 stores + 4 loads
        {
            const unsigned char* bq = bp + 2048;
            ldB(br[3], bq + 98304);  ldA(a1, 0, 32);
            WAITCNT("vmcnt(18) lgkmcnt(4)"); mfma8(a0, br[0]);
            ldB(br[0], bq + 131072); ldA(a0, 0, 64);
            WAITCNT("vmcnt(18) lgkmcnt(4)"); mfma8(a1, br[1]);
            ldB(br[1], bq + 163840); ldA(a1, 0, 96);
            WAITCNT("vmcnt(18) lgkmcnt(4)"); mfma8(a0, br[2]);
            ldB(br[2], bq + 196608); ldA(a0, 128, 0);
            WAITCNT("vmcnt(6) lgkmcnt(4)");  mfma8(a1, br[3]);
        }
        // chunk1 kq 9..14 (vk 36..59)
        #pragma unroll 1
        for (int kq = 1; kq < 7; ++kq) {
            const unsigned char* bq = bp + 2048 + kq * 131072;
            const int ka = kq * 128;
            ldB(br[3], bq + 98304);  ldA(a1, ka, 32);
            WAITCNT("vmcnt(6) lgkmcnt(4)");  mfma8(a0, br[0]);
            ldB(br[0], bq + 131072); ldA(a0, ka, 64);
            WAITCNT("vmcnt(6) lgkmcnt(4)");  mfma8(a1, br[1]);
            ldB(br[1], bq + 163840); ldA(a1, ka, 96);
            WAITCNT("vmcnt(6) lgkmcnt(4)");  mfma8(a0, br[2]);
            ldB(br[2], bq + 196608); ldA(a0, ka + 128, 0);
            WAITCNT("vmcnt(6) lgkmcnt(4)");  mfma8(a1, br[3]);
        }
        // kq15 tail (vk 60..63)
        {
            const unsigned char* bq = bp + 2048 + 7 * 131072;
            const int ka = 7 * 128;
            ldB(br[3], bq + 98304);  ldA(a1, ka, 32);
            WAITCNT("vmcnt(6) lgkmcnt(4)");  mfma8(a0, br[0]);
            ldA(a0, ka, 64);
            WAITCNT("vmcnt(4) lgkmcnt(4)");  mfma8(a1, br[1]);
            ldA(a1, ka, 96);
            WAITCNT("vmcnt(2) lgkmcnt(4)");  mfma8(a0, br[2]);
            WAITCNT("vmcnt(0) lgkmcnt(0)");  mfma8(a1, br[3]);
        }
        __builtin_amdgcn_sched_barrier(0);
        epilogue(ctb0 + 2);
    }
}

extern "C" void kernel_launch(void* const* d_in, const int* in_sizes, int n_in,
                              void* d_out, int out_size, void* d_ws, size_t ws_size,
                              hipStream_t stream) {
    const float* hst  = (const float*)d_in[0];
    const float* epos = (const float*)d_in[1];
    const float* Wsp  = (const float*)d_in[4];
    const float* bsp  = (const float*)d_in[5];
    const float* Wp1  = (const float*)d_in[20];
    const float* bp1  = (const float*)d_in[21];
    const float* gp1  = (const float*)d_in[22];
    const float* btp1 = (const float*)d_in[23];
    const float* mp1  = (const float*)d_in[24];
    const float* vp1  = (const float*)d_in[25];
    const float* Wp2  = (const float*)d_in[26];
    const float* bp2  = (const float*)d_in[27];
    const float* gp2  = (const float*)d_in[28];
    const float* btp2 = (const float*)d_in[29];
    const float* mp2  = (const float*)d_in[30];
    const float* vp2  = (const float*)d_in[31];
    unsigned char* ws = (unsigned char*)d_ws;
    float* out = (float*)d_out;

    // 256 (Wp2 pack) + 16 (W1b pack) + 8 (k-consts) + 4 (A2/C2) = 284 blocks
    prep_pack_kernel<<<284, 256, 0, stream>>>(Wsp, bsp, Wp1, bp1, gp1, btp1, mp1, vp1,
                                              Wp2, bp2, gp2, btp2, mp2, vp2, ws);
    // 256 scenes x 2 i-halves, 512 threads (8 waves)
    mm2_kernel<<<512, 512, 0, stream>>>(hst, epos, ws, out);
}